// Round 4
// baseline (461.461 us; speedup 1.0000x reference)
//
#include <hip/hip_runtime.h>
#include <hip/hip_bf16.h>
#include <math.h>

#define NTOK 65536
#define DIM  128
#define NE   9
#define TOPK 3
#define ALPHA_C 1e-4f

using bf16x8 = __attribute__((ext_vector_type(8))) short;
using f32x4  = __attribute__((ext_vector_type(4))) float;

// ws layout (bytes)
static constexpr size_t OFF_MG   = 0;        // 32 f32
static constexpr size_t OFF_CNT  = 128;      // 9 u32
static constexpr size_t OFF_GSUM = 192;      // 9 f32
static constexpr size_t OFF_SB   = 256;      // 9*128 f32 -> 4864
static constexpr size_t OFF_W1T  = 4864;     // 9*128*128 bf16 -> 299776
static constexpr size_t OFF_W2T  = 299776;   // -> 594688

__device__ __forceinline__ unsigned short f2bf(float f) {
    __hip_bfloat16 h = __float2bfloat16(f);
    return *reinterpret_cast<unsigned short*>(&h);
}

// ---------------- K1: market = relu(x@Wr_w + Wr_b); mg[m] = sum_n market[n][m]*Wl_w[n]
__global__ __launch_bounds__(256) void k_market(const float* __restrict__ x,
    const float* __restrict__ Wrw, const float* __restrict__ Wrb,
    const float* __restrict__ Wlw, float* __restrict__ mg_acc)
{
    __shared__ float xs[64 * 128];
    __shared__ float wr[128 * 32];
    __shared__ float part[256][8];
    int tid = threadIdx.x;
    int base = blockIdx.x * 64;

    const float4* x4 = (const float4*)x + (size_t)base * 32;
    float4* xs4 = (float4*)xs;
    for (int i = tid; i < 64 * 32; i += 256) xs4[i] = x4[i];
    const float4* w4 = (const float4*)Wrw;
    float4* wr4 = (float4*)wr;
    for (int i = tid; i < 128 * 32 / 4; i += 256) wr4[i] = w4[i];
    __syncthreads();

    int tok = tid >> 2, sub = tid & 3, m0 = sub * 8;
    float acc[8];
    #pragma unroll
    for (int k = 0; k < 8; ++k) acc[k] = 0.f;
    for (int d = 0; d < 128; ++d) {
        float xv = xs[tok * 128 + d];
        #pragma unroll
        for (int k = 0; k < 8; ++k) acc[k] += xv * wr[d * 32 + m0 + k];
    }
    float wl = Wlw[base + tok];
    #pragma unroll
    for (int k = 0; k < 8; ++k) {
        float v = acc[k] + Wrb[m0 + k];
        part[tid][k] = (v > 0.f ? v : 0.f) * wl;
    }
    __syncthreads();
    if (tid < 32) {
        int m = tid;
        float s = 0.f;
        for (int t = 0; t < 64; ++t) s += part[t * 4 + (m >> 3)][m & 7];
        atomicAdd(&mg_acc[m], s);
    }
}

// ---------------- K_prepw: W1x, W2 -> bf16 transposed [n][k] per expert
__global__ __launch_bounds__(256) void k_prepw(const float* __restrict__ W1,
    const float* __restrict__ W2, unsigned short* __restrict__ W1T,
    unsigned short* __restrict__ W2T)
{
    __shared__ float t1[32][129];
    __shared__ float t2[32][129];
    int e = blockIdx.x;
    int tid = threadIdx.x;
    const float* W1e = W1 + (size_t)e * 20480;   // [160][128], first 128 rows
    const float* W2e = W2 + (size_t)e * 16384;   // [128][128]
    unsigned short* o1 = W1T + (size_t)e * 16384;
    unsigned short* o2 = W2T + (size_t)e * 16384;
    for (int kb = 0; kb < 128; kb += 32) {
        __syncthreads();
        for (int i = tid; i < 32 * 128; i += 256) {
            int k = i >> 7, n = i & 127;
            t1[k][n] = W1e[(size_t)(kb + k) * 128 + n];
            t2[k][n] = W2e[(size_t)(kb + k) * 128 + n];
        }
        __syncthreads();
        for (int i = tid; i < 128 * 32; i += 256) {
            int n = i >> 5, kk = i & 31;
            o1[(size_t)n * 128 + kb + kk] = f2bf(t1[kk][n]);
            o2[(size_t)n * 128 + kb + kk] = f2bf(t2[kk][n]);
        }
    }
}

// ---------------- K4: style_bias[e][h]
__global__ void k_stylebias(const float* __restrict__ styles, const float* __restrict__ W1,
                            const float* __restrict__ b1, float* __restrict__ sb)
{
    int e = blockIdx.x, h = threadIdx.x;
    float acc = b1[e * 128 + h];
    for (int s = 0; s < 32; ++s)
        acc += styles[e * 32 + s] * W1[(size_t)e * 20480 + (size_t)(128 + s) * 128 + h];
    sb[e * 128 + h] = acc;
}

// ---------------- K3: aux loss scalar
__global__ void k_aux(const unsigned* __restrict__ cnt, const float* __restrict__ gsum,
                      float* __restrict__ out)
{
    float a = 0.f;
    for (int e = 0; e < 9; ++e) {
        float fi = (float)cnt[e] * ((float)NE / ((float)TOPK * (float)NTOK));
        float Pi = gsum[e] / (float)NTOK;
        a += fi * Pi;
    }
    out[(size_t)NTOK * DIM] = ALPHA_C * a;
}

// ---------------- K_fused: router + dense 9-expert FFN + gated accumulate + store
// 64 tokens/block, 256 threads (4 waves), wave = 16 tokens x 128 cols.
__global__ __launch_bounds__(256, 4) void k_fused(const float* __restrict__ x,
    const float* __restrict__ rweights, const float* __restrict__ rb,
    const float* __restrict__ mg, const float* __restrict__ Wlb,
    const unsigned short* __restrict__ W1T, const unsigned short* __restrict__ W2T,
    const float* __restrict__ sbg, const float* __restrict__ b2g,
    unsigned* __restrict__ cnt, float* __restrict__ gsum,
    float* __restrict__ out)
{
    __shared__ unsigned short xs[64 * 128];   // 16 KB swizzled bf16 X
    __shared__ unsigned short hs[64 * 128];   // 16 KB swizzled bf16 H; router scratch overlay
    __shared__ float garr[64][12];            // dense gates (3 nonzero/row)
    __shared__ float ce[9];
    __shared__ unsigned lcount[9];
    __shared__ float lgsum[9];

    float* part = (float*)hs;                 // [64][4][9] = 2304 f32 (9216 B)
    float* rwp  = (float*)hs + 2304;          // 160*9 f32 (5760 B) -> 14976 B < 16 KB

    int tid = threadIdx.x;
    int base = blockIdx.x * 64;

    for (int i = tid; i < 160 * 9; i += 256) rwp[i] = rweights[i];
    if (tid < 9) { lcount[tid] = 0u; lgsum[tid] = 0.f; }
    __syncthreads();

    // router partials: 4 threads per token, 32 d each (f32, exact)
    int tok = tid >> 2, sub = tid & 3;
    {
        float acc[9];
        #pragma unroll
        for (int e = 0; e < 9; ++e) acc[e] = 0.f;
        const float* xrow = x + (size_t)(base + tok) * 128 + sub * 32;
        for (int d = 0; d < 32; ++d) {
            float xv = xrow[d];
            #pragma unroll
            for (int e = 0; e < 9; ++e) acc[e] += xv * rwp[(sub * 32 + d) * 9 + e];
        }
        #pragma unroll
        for (int e = 0; e < 9; ++e) part[(tok * 4 + sub) * 9 + e] = acc[e];
    }
    if (tid < 9) {
        float c = rb[tid];
        float wlb = Wlb[0];
        for (int m = 0; m < 32; ++m) c += (mg[m] + wlb) * rwp[(128 + m) * 9 + tid];
        ce[tid] = c;
    }
    // stage X -> swizzled bf16 LDS (L2-warm second read)
    {
        const float4* x4 = (const float4*)x;
        for (int i = tid; i < 64 * 32; i += 256) {
            int row = i >> 5, p = i & 31;
            float4 v = x4[(size_t)(base + row) * 32 + p];
            unsigned short u[4] = { f2bf(v.x), f2bf(v.y), f2bf(v.z), f2bf(v.w) };
            int sw = ((((p >> 1) ^ (row & 7)) << 4) | ((p & 1) << 3));
            *(ushort4*)((char*)xs + row * 256 + sw) = *(ushort4*)u;
        }
    }
    __syncthreads();

    // finalize router: one thread per token
    if (sub == 0) {
        float lg[9];
        #pragma unroll
        for (int e = 0; e < 9; ++e)
            lg[e] = ce[e] + part[(tok * 4 + 0) * 9 + e] + part[(tok * 4 + 1) * 9 + e]
                  + part[(tok * 4 + 2) * 9 + e] + part[(tok * 4 + 3) * 9 + e];
        int used = 0;
        int bi[3]; float bv[3];
        for (int k = 0; k < 3; ++k) {
            float best = -1e30f; int b = -1;
            for (int e = 0; e < 9; ++e)
                if (!((used >> e) & 1) && lg[e] > best) { best = lg[e]; b = e; }
            bi[k] = b; bv[k] = best; used |= 1 << b;
        }
        float p3[3]; float s = 0.f;
        for (int k = 0; k < 3; ++k) { p3[k] = expf(bv[k] - bv[0]); s += p3[k]; }
        #pragma unroll
        for (int e = 0; e < 12; ++e) garr[tok][e] = 0.f;
        for (int k = 0; k < 3; ++k) {
            float g = p3[k] / s;
            garr[tok][bi[k]] = g;
            atomicAdd(&lcount[bi[k]], 1u);
            atomicAdd(&lgsum[bi[k]], g);
        }
    }
    __syncthreads();   // garr ready; hs (part/rwp) free
    if (tid < 9) {
        atomicAdd(&cnt[tid], lcount[tid]);
        atomicAdd(&gsum[tid], lgsum[tid]);
    }

    int lane = tid & 63, w = tid >> 6;
    int cb = lane & 15, kq = lane >> 4;
    int arow = w * 16 + cb;

    f32x4 acc_out[8];
    #pragma unroll
    for (int n = 0; n < 8; ++n) acc_out[n] = (f32x4){0.f, 0.f, 0.f, 0.f};

    #pragma unroll 1
    for (int e = 0; e < 9; ++e) {
        const unsigned short* W1e = W1T + (size_t)e * 16384;
        const unsigned short* W2e = W2T + (size_t)e * 16384;

        f32x4 acc1[8];
        #pragma unroll
        for (int n = 0; n < 8; ++n) acc1[n] = (f32x4){0.f, 0.f, 0.f, 0.f};

        // Phase 1: H_e = relu(X @ W1x_e + sb_e) * g[:,e]
        #pragma unroll
        for (int kk = 0; kk < 4; ++kk) {
            bf16x8 a = *(const bf16x8*)((const char*)xs + arow * 256 + ((((kk * 4 + kq) ^ (arow & 7)) << 4)));
            #pragma unroll
            for (int n = 0; n < 8; ++n) {
                bf16x8 b = *(const bf16x8*)(W1e + (size_t)(n * 16 + cb) * 128 + kk * 32 + kq * 8);
                acc1[n] = __builtin_amdgcn_mfma_f32_16x16x32_bf16(a, b, acc1[n], 0, 0, 0);
            }
        }
        float gv[4];
        #pragma unroll
        for (int r = 0; r < 4; ++r) gv[r] = garr[w * 16 + kq * 4 + r][e];
        #pragma unroll
        for (int n = 0; n < 8; ++n) {
            int col = n * 16 + cb;
            float sbv = sbg[e * 128 + col];
            #pragma unroll
            for (int r = 0; r < 4; ++r) {
                int row = w * 16 + kq * 4 + r;
                float h = acc1[n][r] + sbv;
                h = (h > 0.f ? h : 0.f) * gv[r];
                int byte = col * 2;
                int sw = ((((byte >> 4) ^ (row & 7)) << 4) | (byte & 15));
                *(unsigned short*)((char*)hs + row * 256 + sw) = f2bf(h);
            }
        }
        __syncthreads();

        // Phase 2: acc_out += H_e @ W2_e   (accumulates across experts)
        #pragma unroll
        for (int kk = 0; kk < 4; ++kk) {
            bf16x8 a = *(const bf16x8*)((const char*)hs + arow * 256 + ((((kk * 4 + kq) ^ (arow & 7)) << 4)));
            #pragma unroll
            for (int n = 0; n < 8; ++n) {
                bf16x8 b = *(const bf16x8*)(W2e + (size_t)(n * 16 + cb) * 128 + kk * 32 + kq * 8);
                acc_out[n] = __builtin_amdgcn_mfma_f32_16x16x32_bf16(a, b, acc_out[n], 0, 0, 0);
            }
        }
        __syncthreads();   // hs consumed; next expert may overwrite
    }

    // epilogue: add sum_e g[t][e]*b2[e][col], store (tokens consecutive -> coalesced-ish)
    #pragma unroll
    for (int n = 0; n < 8; ++n) {
        int col = n * 16 + cb;
        float b2c[9];
        #pragma unroll
        for (int e = 0; e < 9; ++e) b2c[e] = b2g[e * 128 + col];
        #pragma unroll
        for (int r = 0; r < 4; ++r) {
            int row = w * 16 + kq * 4 + r;
            float bias = 0.f;
            #pragma unroll
            for (int e = 0; e < 9; ++e) bias += garr[row][e] * b2c[e];
            out[(size_t)(base + row) * 128 + col] = acc_out[n][r] + bias;
        }
    }
}

extern "C" void kernel_launch(void* const* d_in, const int* in_sizes, int n_in,
                              void* d_out, int out_size, void* d_ws, size_t ws_size,
                              hipStream_t stream) {
    const float* x      = (const float*)d_in[0];
    const float* Wrw    = (const float*)d_in[1];
    const float* Wrb    = (const float*)d_in[2];
    const float* Wlw    = (const float*)d_in[3];
    const float* Wlb    = (const float*)d_in[4];
    const float* rw     = (const float*)d_in[5];
    const float* rb     = (const float*)d_in[6];
    const float* styles = (const float*)d_in[7];
    const float* W1     = (const float*)d_in[8];
    const float* b1     = (const float*)d_in[9];
    const float* W2     = (const float*)d_in[10];
    const float* b2     = (const float*)d_in[11];
    float* out = (float*)d_out;

    char* ws = (char*)d_ws;
    float*          mg    = (float*)(ws + OFF_MG);
    unsigned*       cnt   = (unsigned*)(ws + OFF_CNT);
    float*          gsum  = (float*)(ws + OFF_GSUM);
    float*          sbp   = (float*)(ws + OFF_SB);
    unsigned short* W1T   = (unsigned short*)(ws + OFF_W1T);
    unsigned short* W2T   = (unsigned short*)(ws + OFF_W2T);

    hipMemsetAsync(ws, 0, 256, stream);   // mg, cnt, gsum

    k_market<<<1024, 256, 0, stream>>>(x, Wrw, Wrb, Wlw, mg);
    k_prepw<<<9, 256, 0, stream>>>(W1, W2, W1T, W2T);
    k_stylebias<<<9, 128, 0, stream>>>(styles, W1, b1, sbp);
    k_fused<<<1024, 256, 0, stream>>>(x, rw, rb, mg, Wlb, W1T, W2T, sbp, b2,
                                      cnt, gsum, out);
    k_aux<<<1, 1, 0, stream>>>(cnt, gsum, out);
}